// Round 5
// baseline (201.272 us; speedup 1.0000x reference)
//
#include <hip/hip_runtime.h>

// Committee vote histogram:
//   logits[m,b,c] = x[b,:] . W[m,:,c] + bias[m,c]
//   votes[m,b]    = argmax_c logits
//   out[b,c]      = #{ m : votes[m,b] == c }   (float32)
//
// B=65536, D=512, M=16, C=10.
// Round-5 structure: block = 1024 threads = 16 waves = 4 MODELS x 4 ROW-GROUPS
// (256 rows/block). The 4 waves sharing a model read the SAME W lines
// near-simultaneously -> scalar-L1 line reuse / MSHR merge (R1-R4 had zero
// W-line reuse: every chunk was all-miss, ~45% VALU duty). Per-chunk scalar
// working set = 4 x 1.25 KB = 5 KB << 16 KB sL1. Model-group = blockIdx>>8 so
// co-running blocks share one 80 KB W slice (L2-hot). Partial histograms are
// combined with exact integer-valued float atomicAdd on d_out (pre-zeroed).
// Per-wave inner body identical to the proven R1/R3 codegen (acc[10],
// 40 FMA / kq, no 2-D acc indexing -> no scratch).

#define DDIM    512
#define NCLS    10
#define ROWS    256                 // rows per block (4 groups of 64)
#define KCHUNK  32
#define NCHUNK  (DDIM / KCHUNK)     // 16
#define ROWP    257                 // float4 row stride (odd)

__global__ void zero_out_kernel(float* __restrict__ out, int n)
{
    const int i = blockIdx.x * 1024 + threadIdx.x;
    if (i < n) out[i] = 0.0f;
}

__global__ __launch_bounds__(1024)
void committee_kernel(const float* __restrict__ x,
                      const float* __restrict__ W,
                      const float* __restrict__ bias,
                      float* __restrict__ out)
{
    // xs[buf][kq][row]: x[row0+row][ch*32 + 4*kq .. +3]
    __shared__ float4 xs[2][8][ROWP];
    __shared__ int ihist[ROWS * NCLS];

    const int tid      = threadIdx.x;
    const int rowchunk = blockIdx.x & 255;    // 256 row-chunks
    const int group    = blockIdx.x >> 8;     // 4 model-groups
    const int row0     = rowchunk << 8;       // * ROWS

    for (int i = tid; i < ROWS * NCLS; i += 1024) ihist[i] = 0;

    // tid bits: [5:0]=lane, [7:6]=row-group, [9:8]=model-within-group
    const int m = (group << 2) + __builtin_amdgcn_readfirstlane(tid >> 8);
    const int rowbase = tid & 255;            // rg*64 + lane

    const float* wp = W + (size_t)m * DDIM * NCLS;

    float acc[NCLS];
#pragma unroll
    for (int c = 0; c < NCLS; ++c) acc[c] = bias[m * NCLS + c];

    // staging: thread t loads rows (t>>3) and (t>>3)+128, float4-col t&7
    const int srow = tid >> 3;   // 0..127
    const int skq  = tid & 7;    // 0..7
    const float* gsrc0 = x + (size_t)(row0 + srow) * DDIM + (skq << 2);
    const float* gsrc1 = gsrc0 + (size_t)128 * DDIM;

    // prologue: stage chunk 0 directly, issue loads for chunk 1
    float4 pa0 = *reinterpret_cast<const float4*>(gsrc0);
    float4 pa1 = *reinterpret_cast<const float4*>(gsrc1);
    xs[0][skq][srow]       = pa0;
    xs[0][skq][128 + srow] = pa1;
    pa0 = *reinterpret_cast<const float4*>(gsrc0 + KCHUNK);
    pa1 = *reinterpret_cast<const float4*>(gsrc1 + KCHUNK);

    for (int ch = 0; ch < NCHUNK; ++ch) {
        __syncthreads();           // prev readers of buf[cur^1] done;
        const int cur = ch & 1;    // buf[cur] writes visible

        if (ch + 1 < NCHUNK) {
            // write prefetched chunk ch+1 (load landed during prev compute)
            xs[cur ^ 1][skq][srow]       = pa0;
            xs[cur ^ 1][skq][128 + srow] = pa1;
            if (ch + 2 < NCHUNK) {
                pa0 = *reinterpret_cast<const float4*>(
                    gsrc0 + (size_t)(ch + 2) * KCHUNK);
                pa1 = *reinterpret_cast<const float4*>(
                    gsrc1 + (size_t)(ch + 2) * KCHUNK);
            }
        }

#pragma unroll
        for (int kq = 0; kq < 8; ++kq) {
            const float4 xv = xs[cur][kq][rowbase];
            const float xarr[4] = {xv.x, xv.y, xv.z, xv.w};
            // W chunk for this wave's model: wave-uniform -> s_load
            const float* wk = wp + (size_t)(ch * KCHUNK + (kq << 2)) * NCLS;
#pragma unroll
            for (int j = 0; j < 4; ++j) {
                const float xj = xarr[j];
#pragma unroll
                for (int c = 0; c < NCLS; ++c)
                    acc[c] = fmaf(xj, wk[j * NCLS + c], acc[c]);
            }
        }
    }

    // argmax, first-occurrence-of-max semantics (strict >)
    int best = 0;
    float bv = acc[0];
#pragma unroll
    for (int c = 1; c < NCLS; ++c) {
        if (acc[c] > bv) { bv = acc[c]; best = c; }
    }
    atomicAdd(&ihist[rowbase * NCLS + best], 1);
    __syncthreads();

    // combine partial histogram into global (exact: integer-valued floats)
    for (int i = tid; i < ROWS * NCLS; i += 1024) {
        atomicAdd(&out[(size_t)row0 * NCLS + i], (float)ihist[i]);
    }
}

extern "C" void kernel_launch(void* const* d_in, const int* in_sizes, int n_in,
                              void* d_out, int out_size, void* d_ws, size_t ws_size,
                              hipStream_t stream) {
    const float* x  = (const float*)d_in[0];   // [65536, 512]
    const float* W  = (const float*)d_in[1];   // [16, 512, 10]
    const float* b  = (const float*)d_in[2];   // [16, 10]
    float* out      = (float*)d_out;           // [65536, 10]

    zero_out_kernel<<<(out_size + 1023) / 1024, 1024, 0, stream>>>(out, out_size);

    // 256 row-chunks x 4 model-groups
    committee_kernel<<<1024, 1024, 0, stream>>>(x, W, b, out);
}